// Round 3
// baseline (328.287 us; speedup 1.0000x reference)
//
#include <hip/hip_runtime.h>

typedef __attribute__((ext_vector_type(8))) short short8;
typedef __attribute__((ext_vector_type(4))) float float4v;

// fp32 -> bf16, round-to-nearest-even
__device__ inline short f2bf(float f) {
    union { float f; unsigned int u; } c; c.f = f;
    unsigned int u = c.u;
    unsigned int r = (u + 0x7fffu + ((u >> 16) & 1u)) >> 16;
    return (short)r;
}

// ---------------------------------------------------------------------------
// Kernel 0: W fp32 [1024][64] x3 -> Wt bf16 [192][1024] (n-major), via LDS
// transpose. 48 blocks x 256 thr; coalesced fp32 loads, vector bf16 stores.
// ---------------------------------------------------------------------------
__global__ __launch_bounds__(256) void wconv_kernel(
    const float* __restrict__ Wq, const float* __restrict__ Wk,
    const float* __restrict__ Wv, short* __restrict__ Wt)
{
    __shared__ short Ls[64 * 72];          // [k][c]
    const int w  = blockIdx.x >> 4;        // which W
    const int k0 = (blockIdx.x & 15) * 64; // k chunk
    const float* W = (w == 0) ? Wq : (w == 1) ? Wk : Wv;
    const int tid = threadIdx.x;

    // load 64k x 64c fp32 tile coalesced, convert, store [k][c]
#pragma unroll
    for (int i = 0; i < 4; i++) {
        int kk = (tid >> 4) + i * 16;
        int c4 = (tid & 15) * 4;
        float4 v = *(const float4*)&W[(size_t)(k0 + kk) * 64 + c4];
        Ls[kk * 72 + c4 + 0] = f2bf(v.x);
        Ls[kk * 72 + c4 + 1] = f2bf(v.y);
        Ls[kk * 72 + c4 + 2] = f2bf(v.z);
        Ls[kk * 72 + c4 + 3] = f2bf(v.w);
    }
    __syncthreads();
    // write transposed: thread = (n = tid>>2, k-16-group = tid&3)
    const int n  = tid >> 2;
    const int k8 = (tid & 3) * 16;
    short8 o0, o1;
#pragma unroll
    for (int j = 0; j < 8; j++) o0[j] = Ls[(k8 + j) * 72 + n];
#pragma unroll
    for (int j = 0; j < 8; j++) o1[j] = Ls[(k8 + 8 + j) * 72 + n];
    short* dst = &Wt[(size_t)(w * 64 + n) * 1024 + k0 + k8];
    *(short8*)dst = o0;
    *(short8*)(dst + 8) = o1;
}

// ---------------------------------------------------------------------------
// Kernel 1: fused QKV projection, barrier-free streaming register GEMM.
// X[32768,1024] fp32 @ Wt[192][1024] bf16 -> q,k bf16 [32768,64]; v bf16
// transposed [16][64][2048].
// 1024 blocks x 4 waves. Block = 32 M-rows (shared by all 4 waves -> L1
// dedups A refetch); wave = N-quarter (48 cols = 3 tiles). No LDS, no
// __syncthreads: A-loads (HBM) and B-loads (L2-hot Wt) pipeline freely.
// ---------------------------------------------------------------------------
__global__ __launch_bounds__(256) void qkv_kernel(
    const float* __restrict__ x, const short* __restrict__ Wt,
    short* __restrict__ qo, short* __restrict__ ko, short* __restrict__ vT)
{
    const int tid  = threadIdx.x;
    const int wave = tid >> 6, lane = tid & 63;
    const int quad = lane >> 4, l16 = lane & 15;
    const int m0   = blockIdx.x * 32;
    const int n0   = wave * 48;

    float4v acc[2][3];
#pragma unroll
    for (int mf = 0; mf < 2; mf++)
#pragma unroll
        for (int nt = 0; nt < 3; nt++) acc[mf][nt] = (float4v)0.0f;

    const float* ap0 = &x[(size_t)(m0 + l16) * 1024 + quad * 8];
    const float* ap1 = ap0 + (size_t)16 * 1024;
    const short* bp  = &Wt[(size_t)(n0 + l16) * 1024 + quad * 8];

#pragma unroll 2
    for (int k = 0; k < 1024; k += 32) {
        short8 af[2];
#pragma unroll
        for (int mf = 0; mf < 2; mf++) {
            const float* ap = (mf == 0) ? ap0 : ap1;
            float4 x0 = *(const float4*)(ap + k);
            float4 x1 = *(const float4*)(ap + k + 4);
            short8 a;
            a[0]=f2bf(x0.x); a[1]=f2bf(x0.y); a[2]=f2bf(x0.z); a[3]=f2bf(x0.w);
            a[4]=f2bf(x1.x); a[5]=f2bf(x1.y); a[6]=f2bf(x1.z); a[7]=f2bf(x1.w);
            af[mf] = a;
        }
#pragma unroll
        for (int nt = 0; nt < 3; nt++) {
            short8 bf = *(const short8*)(bp + (size_t)nt * 16 * 1024 + k);
            acc[0][nt] = __builtin_amdgcn_mfma_f32_16x16x32_bf16(af[0], bf, acc[0][nt], 0, 0, 0);
            acc[1][nt] = __builtin_amdgcn_mfma_f32_16x16x32_bf16(af[1], bf, acc[1][nt], 0, 0, 0);
        }
    }
    // epilogue: C/D layout col=l16, row=quad*4+r; route by global col
#pragma unroll
    for (int mf = 0; mf < 2; mf++) {
        int row0 = m0 + mf * 16 + quad * 4;
#pragma unroll
        for (int nt = 0; nt < 3; nt++) {
            int g = n0 + nt * 16 + l16;   // 0..191, range uniform per (wave,nt)
#pragma unroll
            for (int r = 0; r < 4; r++) {
                short val = f2bf(acc[mf][nt][r]);
                int row = row0 + r;
                if (g < 64)       qo[(size_t)row * 64 + g] = val;
                else if (g < 128) ko[(size_t)row * 64 + (g - 64)] = val;
                else {
                    int bb = row >> 11, tt = row & 2047;
                    vT[((size_t)bb * 64 + (g - 128)) * 2048 + tt] = val;
                }
            }
        }
    }
}

// ---------------------------------------------------------------------------
// Kernel 2: flash attention, causal, D=64, scale = 1/32 folded into exp2.
// No max-subtraction (|logit| <~ 1, fp32-exact). Q-frags in registers.
// qt remapped so heavy (qt>=16) and light (qt<16) tiles are in opposite
// dispatch halves -> balanced CU load at 2 blocks/CU.
// ---------------------------------------------------------------------------
#define DSTR 72
#define PSTR 76
#define SCALE_LOG2E 0.04508422132f   // (1/32) * log2(e)

__global__ __launch_bounds__(256) void attn_kernel(
    const short* __restrict__ q, const short* __restrict__ k,
    const short* __restrict__ vT, float* __restrict__ out)
{
    __shared__ short Ks [64 * DSTR];   // [s][d]
    __shared__ short VsT[64 * DSTR];   // [d][s]
    __shared__ short Ps [64 * PSTR];   // [m][s], wave-private 16-row slabs

    const int tid  = threadIdx.x;
    const int wave = tid >> 6, lane = tid & 63;
    const int quad = lane >> 4, l16 = lane & 15;

    int b, qt;
    if (blockIdx.x < 256) { b = blockIdx.x >> 4; qt = 16 + (blockIdx.x & 15); }
    else { int t = blockIdx.x - 256; b = t >> 4; qt = 15 - (t & 15); }

    const short* kb  = k  + (size_t)b * 2048 * 64;
    const short* vTb = vT + (size_t)b * 64 * 2048;

    const short* qrow = q + ((size_t)b * 2048 + qt*64 + wave*16 + l16) * 64;
    short8 qf0 = *(const short8*)&qrow[quad*8];
    short8 qf1 = *(const short8*)&qrow[32 + quad*8];

    float4v oacc[4];
#pragma unroll
    for (int t = 0; t < 4; t++) oacc[t] = (float4v)0.0f;
    float l_i[4] = {0.f, 0.f, 0.f, 0.f};

    const int tg = qt*64 + wave*16 + quad*4;

    for (int j = 0; j <= qt; j++) {
        __syncthreads();
#pragma unroll
        for (int i = 0; i < 2; i++) {
            int c = tid + i * 256;
            int s = c >> 3, d8 = (c & 7) * 8;
            *(short8*)&Ks[s * DSTR + d8] =
                *(const short8*)&kb[(size_t)(j*64 + s) * 64 + d8];
        }
#pragma unroll
        for (int i = 0; i < 2; i++) {
            int c = tid + i * 256;
            int d = c >> 3, s8 = (c & 7) * 8;
            *(short8*)&VsT[d * DSTR + s8] =
                *(const short8*)&vTb[(size_t)d * 2048 + j*64 + s8];
        }
        __syncthreads();

        // --- S = Q K^T ---
        float4v sacc[4];
#pragma unroll
        for (int t = 0; t < 4; t++) sacc[t] = (float4v)0.0f;
#pragma unroll
        for (int t = 0; t < 4; t++) {
            short8 bf0 = *(const short8*)&Ks[(t*16 + l16) * DSTR + quad*8];
            short8 bf1 = *(const short8*)&Ks[(t*16 + l16) * DSTR + 32 + quad*8];
            sacc[t] = __builtin_amdgcn_mfma_f32_16x16x32_bf16(qf0, bf0, sacc[t], 0, 0, 0);
            sacc[t] = __builtin_amdgcn_mfma_f32_16x16x32_bf16(qf1, bf1, sacc[t], 0, 0, 0);
        }
        // --- p = exp2(s * c); diagonal tile masked; l partials in regs ---
        if (j == qt) {
#pragma unroll
            for (int t = 0; t < 4; t++) {
                int sg = j*64 + t*16 + l16;
#pragma unroll
                for (int r = 0; r < 4; r++) {
                    float p = exp2f(sacc[t][r] * SCALE_LOG2E);
                    if (sg > tg + r) p = 0.0f;
                    sacc[t][r] = p;
                    l_i[r] += p;
                }
            }
        } else {
#pragma unroll
            for (int t = 0; t < 4; t++)
#pragma unroll
                for (int r = 0; r < 4; r++) {
                    float p = exp2f(sacc[t][r] * SCALE_LOG2E);
                    sacc[t][r] = p;
                    l_i[r] += p;
                }
        }
        // --- P (C-layout) -> LDS -> A-layout ---
#pragma unroll
        for (int t = 0; t < 4; t++)
#pragma unroll
            for (int r = 0; r < 4; r++)
                Ps[(wave*16 + quad*4 + r) * PSTR + t*16 + l16] = f2bf(sacc[t][r]);
        // --- O += P V ---
#pragma unroll
        for (int kc = 0; kc < 2; kc++) {
            short8 af = *(const short8*)&Ps[(wave*16 + l16) * PSTR + kc*32 + quad*8];
#pragma unroll
            for (int t = 0; t < 4; t++) {
                short8 bf = *(const short8*)&VsT[(t*16 + l16) * DSTR + kc*32 + quad*8];
                oacc[t] = __builtin_amdgcn_mfma_f32_16x16x32_bf16(af, bf, oacc[t], 0, 0, 0);
            }
        }
    }
#pragma unroll
    for (int off = 1; off < 16; off <<= 1)
#pragma unroll
        for (int r = 0; r < 4; r++)
            l_i[r] += __shfl_xor(l_i[r], off, 64);
#pragma unroll
    for (int r = 0; r < 4; r++) {
        float inv = 1.0f / l_i[r];
        int row = qt*64 + wave*16 + quad*4 + r;
#pragma unroll
        for (int t = 0; t < 4; t++)
            out[((size_t)b * 2048 + row) * 64 + t*16 + l16] = oacc[t][r] * inv;
    }
}

extern "C" void kernel_launch(void* const* d_in, const int* in_sizes, int n_in,
                              void* d_out, int out_size, void* d_ws, size_t ws_size,
                              hipStream_t stream)
{
    const float* x  = (const float*)d_in[0];
    const float* Wq = (const float*)d_in[1];
    const float* Wk = (const float*)d_in[2];
    const float* Wv = (const float*)d_in[3];

    short* qw = (short*)d_ws;                       // bf16 [32768,64]
    short* kw = qw + (size_t)32768 * 64;            // bf16 [32768,64]
    short* vT = kw + (size_t)32768 * 64;            // bf16 [16][64][2048]
    short* Wt = vT + (size_t)32768 * 64;            // bf16 [192][1024]
    float* out = (float*)d_out;

    hipLaunchKernelGGL(wconv_kernel, dim3(48), dim3(256), 0, stream,
                       Wq, Wk, Wv, Wt);
    hipLaunchKernelGGL(qkv_kernel, dim3(1024), dim3(256), 0, stream,
                       x, Wt, qw, kw, vT);
    hipLaunchKernelGGL(attn_kernel, dim3(512), dim3(256), 0, stream,
                       qw, kw, vT, out);
}

// Round 4
// 251.905 us; speedup vs baseline: 1.3032x; 1.3032x over previous
//
#include <hip/hip_runtime.h>

typedef __attribute__((ext_vector_type(8))) short short8;
typedef __attribute__((ext_vector_type(4))) float float4v;

// fp32 -> bf16, round-to-nearest-even
__device__ inline short f2bf(float f) {
    union { float f; unsigned int u; } c; c.f = f;
    unsigned int u = c.u;
    unsigned int r = (u + 0x7fffu + ((u >> 16) & 1u)) >> 16;
    return (short)r;
}

// async 16B/lane global->LDS. Pass per-lane pointers (g + lane*16B,
// l + lane*16B); HW semantics: wave-uniform LDS base + lane*16.
__device__ inline void gl2lds16(const short* g, short* l) {
    __builtin_amdgcn_global_load_lds(
        (const __attribute__((address_space(1))) unsigned int*)g,
        (__attribute__((address_space(3))) unsigned int*)l, 16, 0, 0);
}

// Swizzle convention for bf16 rows of 64 elements (8 groups of 8 shorts):
// element (row, col) stored at group (col>>3) ^ (row&7). Makes unpadded
// stride-64 LDS b128 frag reads 2-way (free) AND keeps rows contiguous for
// global_load_lds staging.

// ---------------------------------------------------------------------------
// Kernel 0: W fp32 [1024][64] x3 -> Wt_s bf16, chunk-major swizzled:
// [kchunk 16][n 192][64], element (n, k) at group ((k&63)>>3)^(n&7).
// ---------------------------------------------------------------------------
__global__ __launch_bounds__(256) void wconv_kernel(
    const float* __restrict__ Wq, const float* __restrict__ Wk,
    const float* __restrict__ Wv, short* __restrict__ Wt_s)
{
    __shared__ short Ls[64 * 72];          // [k][c]
    const int w  = blockIdx.x >> 4;        // which W
    const int c  = blockIdx.x & 15;        // k chunk
    const int k0 = c * 64;
    const float* W = (w == 0) ? Wq : (w == 1) ? Wk : Wv;
    const int tid = threadIdx.x;

#pragma unroll
    for (int i = 0; i < 4; i++) {
        int kk = (tid >> 4) + i * 16;
        int c4 = (tid & 15) * 4;
        float4 v = *(const float4*)&W[(size_t)(k0 + kk) * 64 + c4];
        Ls[kk * 72 + c4 + 0] = f2bf(v.x);
        Ls[kk * 72 + c4 + 1] = f2bf(v.y);
        Ls[kk * 72 + c4 + 2] = f2bf(v.z);
        Ls[kk * 72 + c4 + 3] = f2bf(v.w);
    }
    __syncthreads();
    const int n  = tid >> 2;               // 0..63 local
    const int k8 = (tid & 3) * 16;         // local k within chunk
    short8 o0, o1;
#pragma unroll
    for (int j = 0; j < 8; j++) o0[j] = Ls[(k8 + j) * 72 + n];
#pragma unroll
    for (int j = 0; j < 8; j++) o1[j] = Ls[(k8 + 8 + j) * 72 + n];
    const int gn = w * 64 + n;
    short* base = &Wt_s[((size_t)c * 192 + gn) * 64];
    int g0 = k8 >> 3;
    *(short8*)&base[((g0    ) ^ (gn & 7)) * 8] = o0;
    *(short8*)&base[((g0 + 1) ^ (gn & 7)) * 8] = o1;
}

// ---------------------------------------------------------------------------
// Kernel 1: fused QKV projection. X[32768,1024] fp32 @ Wt_s -> q bf16 natural
// [32768][64]; k_s bf16 swizzled [32768][64]; vT_t bf16 [b][tchunk 32][d 64][64sw].
// 1024 blocks x 256 thr (4 blocks/CU, 16 waves/CU). Block = 32 M rows, all
// 192 N; wave = 32 M x 48 N. B staged via global_load_lds from chunk-major
// Wt_s; A staged manually (fp32->bf16) at stride 72.
// ---------------------------------------------------------------------------
__global__ __launch_bounds__(256) void qkv_kernel(
    const float* __restrict__ x, const short* __restrict__ Wt_s,
    short* __restrict__ qo, short* __restrict__ k_s, short* __restrict__ vT_t)
{
    __shared__ short As[32 * 72];
    __shared__ short Bs[192 * 64];

    const int tid  = threadIdx.x;
    const int wave = tid >> 6, lane = tid & 63;
    const int quad = lane >> 4, l16 = lane & 15;
    const int m0   = blockIdx.x * 32;

    float4v acc[2][3];
#pragma unroll
    for (int mf = 0; mf < 2; mf++)
#pragma unroll
        for (int nt = 0; nt < 3; nt++) acc[mf][nt] = (float4v)0.0f;

    const int arow = tid >> 3;            // 0..31
    const int acol = (tid & 7) * 8;       // 0..56
    const float* ap = &x[(size_t)(m0 + arow) * 1024 + acol];
    const int lofs = lane * 8;            // lane*16 B in shorts

    for (int kc = 0; kc < 1024; kc += 64) {
        __syncthreads();
        // A: 32 rows x 64 k fp32 -> bf16, coalesced
        float4 x0 = *(const float4*)(ap + kc);
        float4 x1 = *(const float4*)(ap + kc + 4);
        short8 av;
        av[0]=f2bf(x0.x); av[1]=f2bf(x0.y); av[2]=f2bf(x0.z); av[3]=f2bf(x0.w);
        av[4]=f2bf(x1.x); av[5]=f2bf(x1.y); av[6]=f2bf(x1.z); av[7]=f2bf(x1.w);
        *(short8*)&As[arow * 72 + acol] = av;
        // B: 192 x 64 via async global->LDS (source is chunk-major swizzled)
        const short* gsrc = Wt_s + ((size_t)(kc >> 6) * 192 + wave * 48) * 64;
        short* ldst = &Bs[wave * 48 * 64];
#pragma unroll
        for (int i = 0; i < 6; i++)
            gl2lds16(gsrc + i * 512 + lofs, ldst + i * 512 + lofs);
        __syncthreads();
        // MFMA
#pragma unroll
        for (int kc2 = 0; kc2 < 2; kc2++) {
            short8 a0 = *(const short8*)&As[(l16)      * 72 + kc2*32 + quad*8];
            short8 a1 = *(const short8*)&As[(16 + l16) * 72 + kc2*32 + quad*8];
#pragma unroll
            for (int nt = 0; nt < 3; nt++) {
                int brow = wave * 48 + nt * 16 + l16;
                int g = kc2 * 4 + quad;
                short8 bf = *(const short8*)&Bs[brow * 64 + (g ^ (brow & 7)) * 8];
                acc[0][nt] = __builtin_amdgcn_mfma_f32_16x16x32_bf16(a0, bf, acc[0][nt], 0, 0, 0);
                acc[1][nt] = __builtin_amdgcn_mfma_f32_16x16x32_bf16(a1, bf, acc[1][nt], 0, 0, 0);
            }
        }
    }
    // epilogue: C/D col=l16, row=quad*4+r; route by global col, swizzle k/v
#pragma unroll
    for (int mf = 0; mf < 2; mf++) {
#pragma unroll
        for (int nt = 0; nt < 3; nt++) {
            int g = wave * 48 + nt * 16 + l16;
#pragma unroll
            for (int r = 0; r < 4; r++) {
                int row = m0 + mf * 16 + quad * 4 + r;
                short val = f2bf(acc[mf][nt][r]);
                if (g < 64) {
                    qo[(size_t)row * 64 + g] = val;
                } else if (g < 128) {
                    int h = g - 64;
                    k_s[(size_t)row * 64 + (((h >> 3) ^ (row & 7)) * 8 + (h & 7))] = val;
                } else {
                    int h = g - 128;
                    int bb = row >> 11, tt = row & 2047;
                    int tc = tt >> 6, tl = tt & 63;
                    vT_t[(((size_t)bb * 32 + tc) * 64 + h) * 64 +
                         (((tl >> 3) ^ (h & 7)) * 8 + (tl & 7))] = val;
                }
            }
        }
    }
}

// ---------------------------------------------------------------------------
// Kernel 2: flash attention, causal, D=64, scale 1/32 in exp2; no max-sub
// (|logit| ~ 1, fp32-exact). 1024 blocks x 128 thr (2 waves, 32 Q rows) =
// 4 blocks/CU. KV tiles of 64 staged via global_load_lds from swizzled k_s /
// chunk-major vT_t. Heavy/light qt halves paired for balance.
// ---------------------------------------------------------------------------
#define SCALE_LOG2E 0.04508422132f   // (1/32) * log2(e)

__global__ __launch_bounds__(128) void attn_kernel(
    const short* __restrict__ q, const short* __restrict__ k_s,
    const short* __restrict__ vT_t, float* __restrict__ out)
{
    __shared__ short Ks[64 * 64];   // [s][64sw]
    __shared__ short Vs[64 * 64];   // [d][64sw]
    __shared__ short Ps[32 * 72];   // [m][s], wave-private 16-row slabs

    const int tid  = threadIdx.x;
    const int wave = tid >> 6, lane = tid & 63;
    const int quad = lane >> 4, l16 = lane & 15;

    int b, qt;                       // qt indexes 32-row Q blocks (0..63)
    if (blockIdx.x < 512) { b = blockIdx.x >> 5; qt = 32 + (blockIdx.x & 31); }
    else { int t2 = blockIdx.x - 512; b = t2 >> 5; qt = 31 - (t2 & 31); }

    const short* kb = k_s  + (size_t)b * 2048 * 64;
    const short* vb = vT_t + (size_t)b * 32 * 64 * 64;

    const short* qrow = q + ((size_t)b * 2048 + qt*32 + wave*16 + l16) * 64;
    short8 qf0 = *(const short8*)&qrow[quad*8];
    short8 qf1 = *(const short8*)&qrow[32 + quad*8];

    float4v oacc[4];
#pragma unroll
    for (int t = 0; t < 4; t++) oacc[t] = (float4v)0.0f;
    float l_i[4] = {0.f, 0.f, 0.f, 0.f};

    const int tg   = qt*32 + wave*16 + quad*4;
    const int jmax = qt >> 1;
    const int lofs = lane * 8;

    for (int j = 0; j <= jmax; j++) {
        __syncthreads();
        // stage K rows j*64..+64 (wave halves), contiguous source
        const short* kg = kb + ((size_t)j * 64 + wave * 32) * 64;
        short* kl = &Ks[wave * 32 * 64];
#pragma unroll
        for (int i = 0; i < 4; i++)
            gl2lds16(kg + i * 512 + lofs, kl + i * 512 + lofs);
        // stage V chunk j (contiguous 8 KB in vT_t)
        const short* vg = vb + ((size_t)j * 64 + wave * 32) * 64;
        short* vl = &Vs[wave * 32 * 64];
#pragma unroll
        for (int i = 0; i < 4; i++)
            gl2lds16(vg + i * 512 + lofs, vl + i * 512 + lofs);
        __syncthreads();

        // --- S = Q K^T ---
        float4v sacc[4];
#pragma unroll
        for (int t = 0; t < 4; t++) sacc[t] = (float4v)0.0f;
#pragma unroll
        for (int t = 0; t < 4; t++) {
            int brow = t*16 + l16;
            short8 b0 = *(const short8*)&Ks[brow * 64 + ((    quad) ^ (brow & 7)) * 8];
            short8 b1 = *(const short8*)&Ks[brow * 64 + ((4 + quad) ^ (brow & 7)) * 8];
            sacc[t] = __builtin_amdgcn_mfma_f32_16x16x32_bf16(qf0, b0, sacc[t], 0, 0, 0);
            sacc[t] = __builtin_amdgcn_mfma_f32_16x16x32_bf16(qf1, b1, sacc[t], 0, 0, 0);
        }
        // --- p = exp2(s*c); mask only diagonal tile; l partials in regs ---
        if (j == jmax) {
#pragma unroll
            for (int t = 0; t < 4; t++) {
                int sg = j*64 + t*16 + l16;
#pragma unroll
                for (int r = 0; r < 4; r++) {
                    float p = exp2f(sacc[t][r] * SCALE_LOG2E);
                    if (sg > tg + r) p = 0.0f;
                    sacc[t][r] = p;
                    l_i[r] += p;
                }
            }
        } else {
#pragma unroll
            for (int t = 0; t < 4; t++)
#pragma unroll
                for (int r = 0; r < 4; r++) {
                    float p = exp2f(sacc[t][r] * SCALE_LOG2E);
                    sacc[t][r] = p;
                    l_i[r] += p;
                }
        }
        // --- P (C-layout) -> wave-private LDS -> A-layout ---
#pragma unroll
        for (int t = 0; t < 4; t++)
#pragma unroll
            for (int r = 0; r < 4; r++)
                Ps[(wave*16 + quad*4 + r) * 72 + t*16 + l16] = f2bf(sacc[t][r]);
        // --- O += P V ---
#pragma unroll
        for (int kc = 0; kc < 2; kc++) {
            short8 af = *(const short8*)&Ps[(wave*16 + l16) * 72 + kc*32 + quad*8];
#pragma unroll
            for (int t = 0; t < 4; t++) {
                int drow = t*16 + l16;
                short8 bf = *(const short8*)&Vs[drow * 64 + ((kc*4 + quad) ^ (drow & 7)) * 8];
                oacc[t] = __builtin_amdgcn_mfma_f32_16x16x32_bf16(af, bf, oacc[t], 0, 0, 0);
            }
        }
    }
#pragma unroll
    for (int off = 1; off < 16; off <<= 1)
#pragma unroll
        for (int r = 0; r < 4; r++)
            l_i[r] += __shfl_xor(l_i[r], off, 64);
#pragma unroll
    for (int r = 0; r < 4; r++) {
        float inv = 1.0f / l_i[r];
        int row = qt*32 + wave*16 + quad*4 + r;
#pragma unroll
        for (int t = 0; t < 4; t++)
            out[((size_t)b * 2048 + row) * 64 + t*16 + l16] = oacc[t][r] * inv;
    }
}

extern "C" void kernel_launch(void* const* d_in, const int* in_sizes, int n_in,
                              void* d_out, int out_size, void* d_ws, size_t ws_size,
                              hipStream_t stream)
{
    const float* x  = (const float*)d_in[0];
    const float* Wq = (const float*)d_in[1];
    const float* Wk = (const float*)d_in[2];
    const float* Wv = (const float*)d_in[3];

    short* qw   = (short*)d_ws;                     // bf16 [32768,64] natural
    short* ks   = qw + (size_t)32768 * 64;          // bf16 [32768,64] swizzled
    short* vTt  = ks + (size_t)32768 * 64;          // bf16 [16][32][64][64] swizzled
    short* Wts  = vTt + (size_t)32768 * 64;         // bf16 [16][192][64] swizzled
    float* out  = (float*)d_out;

    hipLaunchKernelGGL(wconv_kernel, dim3(48), dim3(256), 0, stream,
                       Wq, Wk, Wv, Wts);
    hipLaunchKernelGGL(qkv_kernel, dim3(1024), dim3(256), 0, stream,
                       x, Wts, qw, ks, vTt);
    hipLaunchKernelGGL(attn_kernel, dim3(1024), dim3(128), 0, stream,
                       qw, ks, vTt, out);
}